// Round 4
// baseline (247.878 us; speedup 1.0000x reference)
//
#include <hip/hip_runtime.h>
#include <hip/hip_bf16.h>

typedef __bf16 v8bf __attribute__((ext_vector_type(8)));
typedef float v4f __attribute__((ext_vector_type(4)));

#define GBL_AS(p) ((const __attribute__((address_space(1))) unsigned int*)(p))
#define LDS_AS(p) ((__attribute__((address_space(3))) unsigned int*)(p))

// ---------------- fp32 -> bf16 cast (x) ----------------
__global__ void cast_f32_bf16(const float* __restrict__ src,
                              __hip_bfloat16* __restrict__ dst, int n) {
  int i = (blockIdx.x * 256 + threadIdx.x) * 4;
  if (i >= n) return;
  float4 f = *(const float4*)(src + i);
  union { __hip_bfloat16 h[4]; uint2 u; } pk;
  pk.h[0] = __float2bfloat16(f.x);
  pk.h[1] = __float2bfloat16(f.y);
  pk.h[2] = __float2bfloat16(f.z);
  pk.h[3] = __float2bfloat16(f.w);
  *(uint2*)(dst + i) = pk.u;
}

// ---------------- fp32 -> bf16 cast, 3 weight tensors in one dispatch ----------------
__global__ void cast_w3(const float* __restrict__ a, const float* __restrict__ b,
                        const float* __restrict__ c, __hip_bfloat16* __restrict__ dst) {
  int seg = blockIdx.x >> 10;
  const float* src = seg == 0 ? a : (seg == 1 ? b : c);
  int i = ((blockIdx.x & 1023) * 256 + threadIdx.x) * 4;
  float4 f = *(const float4*)(src + i);
  union { __hip_bfloat16 h[4]; uint2 u; } pk;
  pk.h[0] = __float2bfloat16(f.x);
  pk.h[1] = __float2bfloat16(f.y);
  pk.h[2] = __float2bfloat16(f.z);
  pk.h[3] = __float2bfloat16(f.w);
  *(uint2*)(dst + seg * 1048576 + i) = pk.u;
}

// ---------------- bf16 transpose (per-batch): [z][rows][cols] -> [z][cols][rows] ----------------
__global__ void transpose_bf16(const __hip_bfloat16* __restrict__ src,
                               __hip_bfloat16* __restrict__ dst,
                               int rows, int cols) {
  __shared__ __hip_bfloat16 t[32][33];
  long boff = (long)blockIdx.z * rows * cols;
  src += boff; dst += boff;
  int c0 = blockIdx.x * 32, r0 = blockIdx.y * 32;
  int x = threadIdx.x;
#pragma unroll
  for (int i = 0; i < 4; ++i) {
    int y = threadIdx.y + i * 8;
    t[y][x] = src[(long)(r0 + y) * cols + (c0 + x)];
  }
  __syncthreads();
#pragma unroll
  for (int i = 0; i < 4; ++i) {
    int y = threadIdx.y + i * 8;
    dst[(long)(c0 + y) * rows + (r0 + x)] = t[x][y];
  }
}

// ---------------- NT GEMM: C[m,n] = f( scale * sum_k A[m,k]*B[n,k] ) ----------------
// 128x128 tile, BK=32, 256 threads (4 waves as 2x2 of 64x64), mfma 16x16x32 bf16.
// Ping-pong LDS double buffer, ONE barrier per K-iter, prefetch issued after the
// barrier so DMA latency overlaps the previous iter's compute (K-loop restructure;
// the 2-barrier m97 shape was latency-bound here at K=1024).
// MODE 0: proj. grid (24,64): x = z*8 + nb8, y = mb. bf16 out.
// MODE 1: scores->P. flat triangular grid (544). p=(n<=m)?exp(s*scale):0, bf16 out,
//         fused row-sum atomicAdd into sums.
// MODE 2: PV. flat paired grid (512), mirrored mb for constant pair work.
//         fp32 out * 1/sums[m].
template<int MODE>
__global__ __launch_bounds__(256, 4)
void gemm_nt(const __hip_bfloat16* __restrict__ A, long sAb, int lda,
             const __hip_bfloat16* __restrict__ B, long sBb, int ldb,
             void* __restrict__ Cv, long sCb, int ldc,
             int K, float scale, float* __restrict__ sums) {
  const int tid = threadIdx.x;
  const int l = tid & 63, w = tid >> 6;
  int z, nb, mb, kend = K;
  if (MODE == 0) {
    z = blockIdx.x >> 3; nb = (blockIdx.x & 7) << 7; mb = blockIdx.y << 7;
  } else if (MODE == 1) {
    const int id = blockIdx.x;
    z = id & 3;
    const int t = id >> 2;                         // 0..135 triangular index
    int m = (int)((__builtin_sqrtf(8.0f * t + 1.0f) - 1.0f) * 0.5f);
    while ((m + 1) * (m + 2) / 2 <= t) ++m;
    while (m * (m + 1) / 2 > t) --m;
    mb = m << 7;
    nb = (t - m * (m + 1) / 2) << 7;
  } else {
    const int id = blockIdx.x;
    const int half = id >> 8, r8 = id & 255;
    const int m = r8 >> 4, low = r8 & 15;
    nb = (low >> 1) << 7;
    z = (half << 1) | (low & 1);
    const int mi = half ? (15 - m) : m;            // mirrored: pair work constant
    mb = mi << 7;
    kend = (mi + 1) << 7;                          // causal K-limit
  }

  A += (long)z * sAb;
  B += (long)z * sBb;

  __shared__ alignas(16) __hip_bfloat16 As[2][128 * 32];
  __shared__ alignas(16) __hip_bfloat16 Bs[2][128 * 32];

  v4f acc[4][4] = {};
  const int wm = (w >> 1) * 64, wn = (w & 1) * 64;

  // per-thread staging coordinates (wave-uniform LDS base + lane*16)
  const int cb0 = w * 64;                          // chunk base, t=0
  const int row0s = (cb0 + l) >> 2, col0s = ((cb0 + l) & 3) << 3;
  const int cb1 = 256 + w * 64;                    // chunk base, t=1
  const int row1s = (cb1 + l) >> 2, col1s = ((cb1 + l) & 3) << 3;

  const __hip_bfloat16* Arow0 = A + (long)(mb + row0s) * lda + col0s;
  const __hip_bfloat16* Arow1 = A + (long)(mb + row1s) * lda + col1s;
  const __hip_bfloat16* Brow0 = B + (long)(nb + row0s) * ldb + col0s;
  const __hip_bfloat16* Brow1 = B + (long)(nb + row1s) * ldb + col1s;

#define STAGE(k0, buf)                                                         \
  do {                                                                         \
    __builtin_amdgcn_global_load_lds(GBL_AS(Arow0 + (k0)),                     \
        LDS_AS(&As[buf][cb0 * 8]), 16, 0, 0);                                  \
    __builtin_amdgcn_global_load_lds(GBL_AS(Brow0 + (k0)),                     \
        LDS_AS(&Bs[buf][cb0 * 8]), 16, 0, 0);                                  \
    __builtin_amdgcn_global_load_lds(GBL_AS(Arow1 + (k0)),                     \
        LDS_AS(&As[buf][cb1 * 8]), 16, 0, 0);                                  \
    __builtin_amdgcn_global_load_lds(GBL_AS(Brow1 + (k0)),                     \
        LDS_AS(&Bs[buf][cb1 * 8]), 16, 0, 0);                                  \
  } while (0)

  STAGE(0, 0);
  int cur = 0;
  for (int k0 = 0; k0 < kend; k0 += 32) {
    __syncthreads();                 // drains cur-tile DMA (vmcnt(0)) + joins prev reads
    if (k0 + 32 < kend) STAGE(k0 + 32, cur ^ 1);

    v8bf af[4], bfr[4];
#pragma unroll
    for (int i = 0; i < 4; ++i) {
      af[i]  = *(const v8bf*)(&As[cur][(wm + i * 16 + (l & 15)) * 32 + ((l >> 4) << 3)]);
      bfr[i] = *(const v8bf*)(&Bs[cur][(wn + i * 16 + (l & 15)) * 32 + ((l >> 4) << 3)]);
    }
#pragma unroll
    for (int i = 0; i < 4; ++i)
#pragma unroll
      for (int j = 0; j < 4; ++j)
        acc[i][j] = __builtin_amdgcn_mfma_f32_16x16x32_bf16(af[i], bfr[j], acc[i][j], 0, 0, 0);
    cur ^= 1;
  }
#undef STAGE

  // epilogue: C/D layout col=lane&15, row=(lane>>4)*4+reg  [m89-verified]
  const int col0 = nb + wn + (l & 15);
  const int row0 = mb + wm + ((l >> 4) << 2);
  if constexpr (MODE == 0) {
    __hip_bfloat16* C = (__hip_bfloat16*)Cv + (long)z * sCb;
#pragma unroll
    for (int i = 0; i < 4; ++i)
#pragma unroll
      for (int r = 0; r < 4; ++r) {
        long ro = (long)(row0 + i * 16 + r) * ldc;
#pragma unroll
        for (int j = 0; j < 4; ++j)
          C[ro + col0 + j * 16] = __float2bfloat16(acc[i][j][r] * scale);
      }
  } else if constexpr (MODE == 1) {
    __hip_bfloat16* C = (__hip_bfloat16*)Cv + (long)z * sCb;
    float* srow = sums + z * 2048;
#pragma unroll
    for (int i = 0; i < 4; ++i)
#pragma unroll
      for (int r = 0; r < 4; ++r) {
        const int m = row0 + i * 16 + r;
        long ro = (long)m * ldc;
        float sp = 0.f;
#pragma unroll
        for (int j = 0; j < 4; ++j) {
          const int n = col0 + j * 16;
          float p = (n <= m) ? __expf(acc[i][j][r] * scale) : 0.0f;
          sp += p;
          C[ro + n] = __float2bfloat16(p);
        }
        sp += __shfl_xor(sp, 1);
        sp += __shfl_xor(sp, 2);
        sp += __shfl_xor(sp, 4);
        sp += __shfl_xor(sp, 8);
        if ((l & 15) == 0) atomicAdd(&srow[m], sp);
      }
  } else {
    float* C = (float*)Cv + (long)z * sCb;
    const float* srow = sums + z * 2048;
#pragma unroll
    for (int i = 0; i < 4; ++i)
#pragma unroll
      for (int r = 0; r < 4; ++r) {
        const int m = row0 + i * 16 + r;
        const float s = 1.0f / srow[m];
        long ro = (long)m * ldc;
#pragma unroll
        for (int j = 0; j < 4; ++j)
          C[ro + col0 + j * 16] = acc[i][j][r] * s;
      }
  }
}

// ---------------- launch ----------------
extern "C" void kernel_launch(void* const* d_in, const int* in_sizes, int n_in,
                              void* d_out, int out_size, void* d_ws, size_t ws_size,
                              hipStream_t stream) {
  const float* x  = (const float*)d_in[0];
  const float* Wq = (const float*)d_in[1];
  const float* Wk = (const float*)d_in[2];
  const float* Wv = (const float*)d_in[3];
  float* out = (float*)d_out;
  char* ws = (char*)d_ws;

  // ws layout (bytes):
  //   qkv bf16 [3][8192][1024]   @ 0          (48 MB)
  //   vT  bf16 [4][1024][2048]   @ 50331648   (16 MB)
  //   xb  bf16 [8192][1024]      @ 67108864   (16 MB, dead after proj)
  //   Wb  bf16 [3][1024][1024]   @ 83886080   ( 6 MB, dead after proj)
  //   P   bf16 [4][2048][2048]   @ 67108864   (32 MB, overlaps dead xb/Wb)
  //   sums fp32 [8192]           @ 100663296  (32 KB)
  __hip_bfloat16* qkv = (__hip_bfloat16*)ws;
  __hip_bfloat16* vT  = (__hip_bfloat16*)(ws + 50331648);
  __hip_bfloat16* xb  = (__hip_bfloat16*)(ws + 67108864);
  __hip_bfloat16* Wb  = (__hip_bfloat16*)(ws + 83886080);
  __hip_bfloat16* P   = (__hip_bfloat16*)(ws + 67108864);
  float* sums         = (float*)(ws + 100663296);

  hipMemsetAsync(sums, 0, 8192 * sizeof(float), stream);

  cast_f32_bf16<<<8192, 256, 0, stream>>>(x, xb, 8388608);
  cast_w3<<<3072, 256, 0, stream>>>(Wq, Wk, Wv, Wb);

  // qkv projections, z folded into x for A-tile/L2 locality
  gemm_nt<0><<<dim3(24, 64, 1), 256, 0, stream>>>(
      xb, 0L, 1024, Wb, 1048576L, 1024, qkv, 8388608L, 1024,
      1024, 1.0f, nullptr);

  // v -> vT (per batch)
  transpose_bf16<<<dim3(32, 64, 4), dim3(32, 8), 0, stream>>>(
      qkv + 16777216, vT, 2048, 1024);

  // P = exp((q@k^T)/32) causal, bf16, fused row-sums (triangular grid: 136*4)
  gemm_nt<1><<<dim3(544, 1, 1), 256, 0, stream>>>(
      qkv, 2097152L, 1024, qkv + 8388608, 2097152L, 1024,
      P, 4194304L, 2048, 1024, 0.03125f, sums);

  // out = (P @ vT^T) / rowsum, causal K-limit, pair-balanced flat grid
  gemm_nt<2><<<dim3(512, 1, 1), 256, 0, stream>>>(
      P, 4194304L, 2048, vT, 2097152L, 2048,
      out, 2097152L, 1024, 2048, 1.0f, sums);
}

// Round 5
// 246.573 us; speedup vs baseline: 1.0053x; 1.0053x over previous
//
#include <hip/hip_runtime.h>
#include <hip/hip_bf16.h>

typedef __bf16 v8bf __attribute__((ext_vector_type(8)));
typedef float v4f __attribute__((ext_vector_type(4)));

#define GBL_AS(p) ((const __attribute__((address_space(1))) unsigned int*)(p))
#define LDS_AS(p) ((__attribute__((address_space(3))) unsigned int*)(p))

// s_waitcnt immediates: lgkmcnt=15 (no wait) bits[11:8], expcnt=7 bits[6:4],
// vmcnt low bits[3:0] (vmcnt<16 here).
#define WAIT_VM4() __builtin_amdgcn_s_waitcnt(0x0F74)  // vmcnt(4)
#define WAIT_VM0() __builtin_amdgcn_s_waitcnt(0x0F70)  // vmcnt(0)

// ---------------- fp32 -> bf16 cast (x) ----------------
__global__ void cast_f32_bf16(const float* __restrict__ src,
                              __hip_bfloat16* __restrict__ dst, int n) {
  int i = (blockIdx.x * 256 + threadIdx.x) * 4;
  if (i >= n) return;
  float4 f = *(const float4*)(src + i);
  union { __hip_bfloat16 h[4]; uint2 u; } pk;
  pk.h[0] = __float2bfloat16(f.x);
  pk.h[1] = __float2bfloat16(f.y);
  pk.h[2] = __float2bfloat16(f.z);
  pk.h[3] = __float2bfloat16(f.w);
  *(uint2*)(dst + i) = pk.u;
}

// ---------------- fp32 -> bf16 cast, 3 weight tensors in one dispatch ----------------
__global__ void cast_w3(const float* __restrict__ a, const float* __restrict__ b,
                        const float* __restrict__ c, __hip_bfloat16* __restrict__ dst) {
  int seg = blockIdx.x >> 10;
  const float* src = seg == 0 ? a : (seg == 1 ? b : c);
  int i = ((blockIdx.x & 1023) * 256 + threadIdx.x) * 4;
  float4 f = *(const float4*)(src + i);
  union { __hip_bfloat16 h[4]; uint2 u; } pk;
  pk.h[0] = __float2bfloat16(f.x);
  pk.h[1] = __float2bfloat16(f.y);
  pk.h[2] = __float2bfloat16(f.z);
  pk.h[3] = __float2bfloat16(f.w);
  *(uint2*)(dst + seg * 1048576 + i) = pk.u;
}

// ---------------- bf16 transpose (per-batch): [z][rows][cols] -> [z][cols][rows] ----------------
__global__ void transpose_bf16(const __hip_bfloat16* __restrict__ src,
                               __hip_bfloat16* __restrict__ dst,
                               int rows, int cols) {
  __shared__ __hip_bfloat16 t[32][33];
  long boff = (long)blockIdx.z * rows * cols;
  src += boff; dst += boff;
  int c0 = blockIdx.x * 32, r0 = blockIdx.y * 32;
  int x = threadIdx.x;
#pragma unroll
  for (int i = 0; i < 4; ++i) {
    int y = threadIdx.y + i * 8;
    t[y][x] = src[(long)(r0 + y) * cols + (c0 + x)];
  }
  __syncthreads();
#pragma unroll
  for (int i = 0; i < 4; ++i) {
    int y = threadIdx.y + i * 8;
    dst[(long)(c0 + y) * rows + (r0 + x)] = t[x][y];
  }
}

// ---------------- NT GEMM: C[m,n] = f( scale * sum_k A[m,k]*B[n,k] ) ----------------
// 128x128 tile, BK=32, 256 threads (4 waves as 2x2 of 64x64), mfma 16x16x32 bf16.
// 3-stage software pipeline: triple LDS buffer, prefetch issued 2 tiles ahead,
// raw s_barrier + explicit s_waitcnt vmcnt(4) so the NEXT tile's DMA stays in
// flight across the barrier (AITER-style "never vmcnt(0)" K-loop).
// Safety: a wave's ds_reads retire before it reaches the barrier (they feed
// pre-barrier MFMAs); the DMA overwriting buf (i-1)%3 is issued after the
// barrier, so all iter-(i-1) reads are complete.
// MODE 0: proj. grid (24,64): x = z*8 + nb8, y = mb. bf16 out.
// MODE 1: scores->P. flat triangular grid (544). p=(n<=m)?exp(s*scale):0, bf16
//         out, fused row-sum atomicAdd into sums.
// MODE 2: PV. flat paired grid (512), mirrored mb for constant pair work.
//         fp32 out * 1/sums[m].
template<int MODE>
__global__ __launch_bounds__(256, 4)
void gemm_nt(const __hip_bfloat16* __restrict__ A, long sAb, int lda,
             const __hip_bfloat16* __restrict__ B, long sBb, int ldb,
             void* __restrict__ Cv, long sCb, int ldc,
             int K, float scale, float* __restrict__ sums) {
  const int tid = threadIdx.x;
  const int l = tid & 63, w = tid >> 6;
  int z, nb, mb, kend = K;
  if (MODE == 0) {
    z = blockIdx.x >> 3; nb = (blockIdx.x & 7) << 7; mb = blockIdx.y << 7;
  } else if (MODE == 1) {
    const int id = blockIdx.x;
    z = id & 3;
    const int t = id >> 2;                         // 0..135 triangular index
    int m = (int)((__builtin_sqrtf(8.0f * t + 1.0f) - 1.0f) * 0.5f);
    while ((m + 1) * (m + 2) / 2 <= t) ++m;
    while (m * (m + 1) / 2 > t) --m;
    mb = m << 7;
    nb = (t - m * (m + 1) / 2) << 7;
  } else {
    const int id = blockIdx.x;
    const int half = id >> 8, r8 = id & 255;
    const int m = r8 >> 4, low = r8 & 15;
    nb = (low >> 1) << 7;
    z = (half << 1) | (low & 1);
    const int mi = half ? (15 - m) : m;            // mirrored: pair work constant
    mb = mi << 7;
    kend = (mi + 1) << 7;                          // causal K-limit
  }

  A += (long)z * sAb;
  B += (long)z * sBb;

  __shared__ alignas(16) __hip_bfloat16 As[3][128 * 32];
  __shared__ alignas(16) __hip_bfloat16 Bs[3][128 * 32];

  v4f acc[4][4] = {};
  const int wm = (w >> 1) * 64, wn = (w & 1) * 64;

  // per-thread staging coordinates (wave-uniform LDS base + lane*16)
  const int cb0 = w * 64;                          // chunk base, t=0
  const int row0s = (cb0 + l) >> 2, col0s = ((cb0 + l) & 3) << 3;
  const int cb1 = 256 + w * 64;                    // chunk base, t=1
  const int row1s = (cb1 + l) >> 2, col1s = ((cb1 + l) & 3) << 3;

  const __hip_bfloat16* Arow0 = A + (long)(mb + row0s) * lda + col0s;
  const __hip_bfloat16* Arow1 = A + (long)(mb + row1s) * lda + col1s;
  const __hip_bfloat16* Brow0 = B + (long)(nb + row0s) * ldb + col0s;
  const __hip_bfloat16* Brow1 = B + (long)(nb + row1s) * ldb + col1s;

  auto stage = [&](int k0, int buf) {
    __builtin_amdgcn_global_load_lds(GBL_AS(Arow0 + k0),
        LDS_AS(&As[buf][cb0 * 8]), 16, 0, 0);
    __builtin_amdgcn_global_load_lds(GBL_AS(Brow0 + k0),
        LDS_AS(&Bs[buf][cb0 * 8]), 16, 0, 0);
    __builtin_amdgcn_global_load_lds(GBL_AS(Arow1 + k0),
        LDS_AS(&As[buf][cb1 * 8]), 16, 0, 0);
    __builtin_amdgcn_global_load_lds(GBL_AS(Brow1 + k0),
        LDS_AS(&Bs[buf][cb1 * 8]), 16, 0, 0);
  };

  stage(0, 0);
  if (32 < kend) stage(32, 1);

  int bi = 0;                                      // buffer holding current tile
  for (int k0 = 0; k0 < kend; k0 += 32) {
    // wait for current tile's 4 loads; leave next tile's 4 in flight
    if (k0 + 32 < kend) WAIT_VM4(); else WAIT_VM0();
    __builtin_amdgcn_s_barrier();
    if (k0 + 64 < kend) stage(k0 + 64, bi == 0 ? 2 : bi - 1);

    v8bf af[4], bfr[4];
#pragma unroll
    for (int i = 0; i < 4; ++i) {
      af[i]  = *(const v8bf*)(&As[bi][(wm + i * 16 + (l & 15)) * 32 + ((l >> 4) << 3)]);
      bfr[i] = *(const v8bf*)(&Bs[bi][(wn + i * 16 + (l & 15)) * 32 + ((l >> 4) << 3)]);
    }
#pragma unroll
    for (int i = 0; i < 4; ++i)
#pragma unroll
      for (int j = 0; j < 4; ++j)
        acc[i][j] = __builtin_amdgcn_mfma_f32_16x16x32_bf16(af[i], bfr[j], acc[i][j], 0, 0, 0);
    bi = (bi == 2) ? 0 : bi + 1;
  }

  // epilogue: C/D layout col=lane&15, row=(lane>>4)*4+reg  [m89-verified]
  const int col0 = nb + wn + (l & 15);
  const int row0 = mb + wm + ((l >> 4) << 2);
  if constexpr (MODE == 0) {
    __hip_bfloat16* C = (__hip_bfloat16*)Cv + (long)z * sCb;
#pragma unroll
    for (int i = 0; i < 4; ++i)
#pragma unroll
      for (int r = 0; r < 4; ++r) {
        long ro = (long)(row0 + i * 16 + r) * ldc;
#pragma unroll
        for (int j = 0; j < 4; ++j)
          C[ro + col0 + j * 16] = __float2bfloat16(acc[i][j][r] * scale);
      }
  } else if constexpr (MODE == 1) {
    __hip_bfloat16* C = (__hip_bfloat16*)Cv + (long)z * sCb;
    float* srow = sums + z * 2048;
#pragma unroll
    for (int i = 0; i < 4; ++i)
#pragma unroll
      for (int r = 0; r < 4; ++r) {
        const int m = row0 + i * 16 + r;
        long ro = (long)m * ldc;
        float sp = 0.f;
#pragma unroll
        for (int j = 0; j < 4; ++j) {
          const int n = col0 + j * 16;
          float p = (n <= m) ? __expf(acc[i][j][r] * scale) : 0.0f;
          sp += p;
          C[ro + n] = __float2bfloat16(p);
        }
        sp += __shfl_xor(sp, 1);
        sp += __shfl_xor(sp, 2);
        sp += __shfl_xor(sp, 4);
        sp += __shfl_xor(sp, 8);
        if ((l & 15) == 0) atomicAdd(&srow[m], sp);
      }
  } else {
    float* C = (float*)Cv + (long)z * sCb;
    const float* srow = sums + z * 2048;
#pragma unroll
    for (int i = 0; i < 4; ++i)
#pragma unroll
      for (int r = 0; r < 4; ++r) {
        const int m = row0 + i * 16 + r;
        const float s = 1.0f / srow[m];
        long ro = (long)m * ldc;
#pragma unroll
        for (int j = 0; j < 4; ++j)
          C[ro + col0 + j * 16] = acc[i][j][r] * s;
      }
  }
}

// ---------------- launch ----------------
extern "C" void kernel_launch(void* const* d_in, const int* in_sizes, int n_in,
                              void* d_out, int out_size, void* d_ws, size_t ws_size,
                              hipStream_t stream) {
  const float* x  = (const float*)d_in[0];
  const float* Wq = (const float*)d_in[1];
  const float* Wk = (const float*)d_in[2];
  const float* Wv = (const float*)d_in[3];
  float* out = (float*)d_out;
  char* ws = (char*)d_ws;

  // ws layout (bytes):
  //   qkv bf16 [3][8192][1024]   @ 0          (48 MB)
  //   vT  bf16 [4][1024][2048]   @ 50331648   (16 MB)
  //   xb  bf16 [8192][1024]      @ 67108864   (16 MB, dead after proj)
  //   Wb  bf16 [3][1024][1024]   @ 83886080   ( 6 MB, dead after proj)
  //   P   bf16 [4][2048][2048]   @ 67108864   (32 MB, overlaps dead xb/Wb)
  //   sums fp32 [8192]           @ 100663296  (32 KB)
  __hip_bfloat16* qkv = (__hip_bfloat16*)ws;
  __hip_bfloat16* vT  = (__hip_bfloat16*)(ws + 50331648);
  __hip_bfloat16* xb  = (__hip_bfloat16*)(ws + 67108864);
  __hip_bfloat16* Wb  = (__hip_bfloat16*)(ws + 83886080);
  __hip_bfloat16* P   = (__hip_bfloat16*)(ws + 67108864);
  float* sums         = (float*)(ws + 100663296);

  hipMemsetAsync(sums, 0, 8192 * sizeof(float), stream);

  cast_f32_bf16<<<8192, 256, 0, stream>>>(x, xb, 8388608);
  cast_w3<<<3072, 256, 0, stream>>>(Wq, Wk, Wv, Wb);

  // qkv projections, z folded into x for A-tile/L2 locality
  gemm_nt<0><<<dim3(24, 64, 1), 256, 0, stream>>>(
      xb, 0L, 1024, Wb, 1048576L, 1024, qkv, 8388608L, 1024,
      1024, 1.0f, nullptr);

  // v -> vT (per batch)
  transpose_bf16<<<dim3(32, 64, 4), dim3(32, 8), 0, stream>>>(
      qkv + 16777216, vT, 2048, 1024);

  // P = exp((q@k^T)/32) causal, bf16, fused row-sums (triangular grid: 136*4)
  gemm_nt<1><<<dim3(544, 1, 1), 256, 0, stream>>>(
      qkv, 2097152L, 1024, qkv + 8388608, 2097152L, 1024,
      P, 4194304L, 2048, 1024, 0.03125f, sums);

  // out = (P @ vT^T) / rowsum, causal K-limit, pair-balanced flat grid
  gemm_nt<2><<<dim3(512, 1, 1), 256, 0, stream>>>(
      P, 4194304L, 2048, vT, 2097152L, 2048,
      out, 2097152L, 1024, 2048, 1.0f, sums);
}

// Round 7
// 235.417 us; speedup vs baseline: 1.0529x; 1.0474x over previous
//
#include <hip/hip_runtime.h>
#include <hip/hip_bf16.h>

typedef __bf16 v8bf __attribute__((ext_vector_type(8)));
typedef float v4f __attribute__((ext_vector_type(4)));

#define GBL_AS(p) ((const __attribute__((address_space(1))) unsigned int*)(p))
#define LDS_AS(p) ((__attribute__((address_space(3))) unsigned int*)(p))

// s_waitcnt immediates: lgkmcnt=15 (no wait) bits[11:8], expcnt=7 bits[6:4],
// vmcnt low bits[3:0].
#define WAIT_VM4() __builtin_amdgcn_s_waitcnt(0x0F74)  // vmcnt(4)
#define WAIT_VM0() __builtin_amdgcn_s_waitcnt(0x0F70)  // vmcnt(0)

// ---------------- fp32 -> bf16 cast (x) ----------------
__global__ void cast_f32_bf16(const float* __restrict__ src,
                              __hip_bfloat16* __restrict__ dst, int n) {
  int i = (blockIdx.x * 256 + threadIdx.x) * 4;
  if (i >= n) return;
  float4 f = *(const float4*)(src + i);
  union { __hip_bfloat16 h[4]; uint2 u; } pk;
  pk.h[0] = __float2bfloat16(f.x);
  pk.h[1] = __float2bfloat16(f.y);
  pk.h[2] = __float2bfloat16(f.z);
  pk.h[3] = __float2bfloat16(f.w);
  *(uint2*)(dst + i) = pk.u;
}

// ---------------- fp32 -> bf16 cast, 3 weight tensors in one dispatch ----------------
__global__ void cast_w3(const float* __restrict__ a, const float* __restrict__ b,
                        const float* __restrict__ c, __hip_bfloat16* __restrict__ dst) {
  int seg = blockIdx.x >> 10;
  const float* src = seg == 0 ? a : (seg == 1 ? b : c);
  int i = ((blockIdx.x & 1023) * 256 + threadIdx.x) * 4;
  float4 f = *(const float4*)(src + i);
  union { __hip_bfloat16 h[4]; uint2 u; } pk;
  pk.h[0] = __float2bfloat16(f.x);
  pk.h[1] = __float2bfloat16(f.y);
  pk.h[2] = __float2bfloat16(f.z);
  pk.h[3] = __float2bfloat16(f.w);
  *(uint2*)(dst + seg * 1048576 + i) = pk.u;
}

// ---------------- NT GEMM: C[m,n] = f( scale * sum_k A[m,k]*B[n,k] ) ----------------
// 128x128 tile, BK=32, 256 threads (4 waves as 2x2 of 64x64), mfma 16x16x32 bf16.
// Triple LDS buffer, raw s_barrier + vmcnt(4) pipeline.
// MODE 0/1 (K=1024 compile-time): K-loop fully unrolled; K-offsets are CONSTANT
//   POINTER ARITHMETIC (offset arg stays 0 — nonzero imm offset on
//   global_load_lds is unverified and NaN'd R6; compiler folds the constants
//   into the global_load imm field itself).
// MODE 0: proj. grid (24,64): x = z*8 + nb8, y = mb. z<2 -> bf16 out to qkv;
//         z==2 -> epilogue writes TRANSPOSED into vT[b][col][seq] (8B packed).
// MODE 1: scores->P. flat triangular grid (544). p=(n<=m)?exp(s*scale):0, bf16
//         out, fused row-sum atomicAdd into sums.
// MODE 2: PV (dynamic K). flat paired grid (512), mirrored mb. fp32 out / sums[m].
template<int MODE>
__global__ __launch_bounds__(256, 3)
void gemm_nt(const __hip_bfloat16* __restrict__ A, long sAb, int lda,
             const __hip_bfloat16* __restrict__ B, long sBb, int ldb,
             void* __restrict__ Cv, long sCb, int ldc,
             int K, float scale, float* __restrict__ sums,
             __hip_bfloat16* __restrict__ vTp) {
  const int tid = threadIdx.x;
  const int l = tid & 63, w = tid >> 6;
  int z, nb, mb, kend = K;
  if (MODE == 0) {
    z = blockIdx.x >> 3; nb = (blockIdx.x & 7) << 7; mb = blockIdx.y << 7;
  } else if (MODE == 1) {
    const int id = blockIdx.x;
    z = id & 3;
    const int t = id >> 2;                         // 0..135 triangular index
    int m = (int)((__builtin_sqrtf(8.0f * t + 1.0f) - 1.0f) * 0.5f);
    while ((m + 1) * (m + 2) / 2 <= t) ++m;
    while (m * (m + 1) / 2 > t) --m;
    mb = m << 7;
    nb = (t - m * (m + 1) / 2) << 7;
  } else {
    const int id = blockIdx.x;
    const int half = id >> 8, r8 = id & 255;
    const int m = r8 >> 4, low = r8 & 15;
    nb = (low >> 1) << 7;
    z = (half << 1) | (low & 1);
    const int mi = half ? (15 - m) : m;            // mirrored: pair work constant
    mb = mi << 7;
    kend = (mi + 1) << 7;                          // causal K-limit
  }

  A += (long)z * sAb;
  B += (long)z * sBb;

  __shared__ alignas(16) __hip_bfloat16 As[3][128 * 32];
  __shared__ alignas(16) __hip_bfloat16 Bs[3][128 * 32];

  v4f acc[4][4] = {};
  const int wm = (w >> 1) * 64, wn = (w & 1) * 64;

  // staging coordinates: chunk c = row*4 + g; LDS dest = wave-uniform base + lane*16
  const int cb0 = w * 64;
  const int row0s = (cb0 + l) >> 2, col0s = ((cb0 + l) & 3) << 3;
  const int cb1 = 256 + w * 64;
  const int row1s = (cb1 + l) >> 2, col1s = ((cb1 + l) & 3) << 3;

  const __hip_bfloat16* Arow0 = A + (long)(mb + row0s) * lda + col0s;
  const __hip_bfloat16* Arow1 = A + (long)(mb + row1s) * lda + col1s;
  const __hip_bfloat16* Brow0 = B + (long)(nb + row0s) * ldb + col0s;
  const __hip_bfloat16* Brow1 = B + (long)(nb + row1s) * ldb + col1s;

  // LDS read bases (lane-dependent part, computed once)
  const int ldsA = (wm + (l & 15)) * 32 + ((l >> 4) << 3);
  const int ldsB = (wn + (l & 15)) * 32 + ((l >> 4) << 3);

  // K0 = element offset (compile-time constant in unrolled path); offset arg 0.
#define STAGE_T(K0, BUF) do {                                                   \
    __builtin_amdgcn_global_load_lds(GBL_AS(Arow0 + (K0)),                      \
        LDS_AS(&As[BUF][cb0 * 8]), 16, 0, 0);                                   \
    __builtin_amdgcn_global_load_lds(GBL_AS(Brow0 + (K0)),                      \
        LDS_AS(&Bs[BUF][cb0 * 8]), 16, 0, 0);                                   \
    __builtin_amdgcn_global_load_lds(GBL_AS(Arow1 + (K0)),                      \
        LDS_AS(&As[BUF][cb1 * 8]), 16, 0, 0);                                   \
    __builtin_amdgcn_global_load_lds(GBL_AS(Brow1 + (K0)),                      \
        LDS_AS(&Bs[BUF][cb1 * 8]), 16, 0, 0);                                   \
  } while (0)

#define COMPUTE(BI) do {                                                        \
    v8bf af[4], bfr[4];                                                         \
    _Pragma("unroll")                                                           \
    for (int i = 0; i < 4; ++i) {                                               \
      af[i]  = *(const v8bf*)(&As[BI][ldsA + i * 512]);                         \
      bfr[i] = *(const v8bf*)(&Bs[BI][ldsB + i * 512]);                         \
    }                                                                           \
    _Pragma("unroll")                                                           \
    for (int i = 0; i < 4; ++i)                                                 \
      _Pragma("unroll")                                                         \
      for (int j = 0; j < 4; ++j)                                               \
        acc[i][j] = __builtin_amdgcn_mfma_f32_16x16x32_bf16(af[i], bfr[j],      \
                                                            acc[i][j], 0, 0, 0);\
  } while (0)

#define KITER(IT) do {                                                          \
    if constexpr ((IT) < 31) WAIT_VM4(); else WAIT_VM0();                       \
    __builtin_amdgcn_s_barrier();                                               \
    if constexpr ((IT) < 30) STAGE_T((IT) * 32 + 64, ((IT) + 2) % 3);           \
    COMPUTE((IT) % 3);                                                          \
  } while (0)

  if constexpr (MODE == 0 || MODE == 1) {
    // K = 1024 = 32 tiles, fully unrolled, constant-folded addresses
    STAGE_T(0, 0);
    STAGE_T(32, 1);
    KITER(0);  KITER(1);  KITER(2);  KITER(3);  KITER(4);  KITER(5);  KITER(6);
    KITER(7);  KITER(8);  KITER(9);  KITER(10); KITER(11); KITER(12); KITER(13);
    KITER(14); KITER(15); KITER(16); KITER(17); KITER(18); KITER(19); KITER(20);
    KITER(21); KITER(22); KITER(23); KITER(24); KITER(25); KITER(26); KITER(27);
    KITER(28); KITER(29); KITER(30); KITER(31);
  } else {
    // dynamic K (PV): rolling 3-buffer pipeline
    auto stage = [&](int k0, int buf) {
      __builtin_amdgcn_global_load_lds(GBL_AS(Arow0 + k0),
          LDS_AS(&As[buf][cb0 * 8]), 16, 0, 0);
      __builtin_amdgcn_global_load_lds(GBL_AS(Brow0 + k0),
          LDS_AS(&Bs[buf][cb0 * 8]), 16, 0, 0);
      __builtin_amdgcn_global_load_lds(GBL_AS(Arow1 + k0),
          LDS_AS(&As[buf][cb1 * 8]), 16, 0, 0);
      __builtin_amdgcn_global_load_lds(GBL_AS(Brow1 + k0),
          LDS_AS(&Bs[buf][cb1 * 8]), 16, 0, 0);
    };
    stage(0, 0);
    if (32 < kend) stage(32, 1);
    int bi = 0;
    for (int k0 = 0; k0 < kend; k0 += 32) {
      if (k0 + 32 < kend) WAIT_VM4(); else WAIT_VM0();
      __builtin_amdgcn_s_barrier();
      if (k0 + 64 < kend) stage(k0 + 64, bi == 0 ? 2 : bi - 1);
      v8bf af[4], bfr[4];
#pragma unroll
      for (int i = 0; i < 4; ++i) {
        af[i]  = *(const v8bf*)(&As[bi][ldsA + i * 512]);
        bfr[i] = *(const v8bf*)(&Bs[bi][ldsB + i * 512]);
      }
#pragma unroll
      for (int i = 0; i < 4; ++i)
#pragma unroll
        for (int j = 0; j < 4; ++j)
          acc[i][j] = __builtin_amdgcn_mfma_f32_16x16x32_bf16(af[i], bfr[j], acc[i][j], 0, 0, 0);
      bi = (bi == 2) ? 0 : bi + 1;
    }
  }
#undef KITER
#undef COMPUTE
#undef STAGE_T

  // epilogue: C/D layout col=lane&15, row=(lane>>4)*4+reg  [m89-verified]
  const int col0 = nb + wn + (l & 15);
  const int row0 = mb + wm + ((l >> 4) << 2);
  if constexpr (MODE == 0) {
    if (z < 2) {
      __hip_bfloat16* C = (__hip_bfloat16*)Cv + (long)z * sCb;
#pragma unroll
      for (int i = 0; i < 4; ++i)
#pragma unroll
        for (int r = 0; r < 4; ++r) {
          long ro = (long)(row0 + i * 16 + r) * ldc;
#pragma unroll
          for (int j = 0; j < 4; ++j)
            C[ro + col0 + j * 16] = __float2bfloat16(acc[i][j][r] * scale);
        }
    } else {
      // V projection: write transposed into vT[b][col][seq], 8B packed stores
      const long b = row0 >> 11;
      const int seq0 = row0 & 2047;
#pragma unroll
      for (int i = 0; i < 4; ++i)
#pragma unroll
        for (int j = 0; j < 4; ++j) {
          union { __hip_bfloat16 h[4]; uint2 u; } pk;
#pragma unroll
          for (int r = 0; r < 4; ++r) pk.h[r] = __float2bfloat16(acc[i][j][r]);
          *(uint2*)(vTp + b * 2097152 + (long)(col0 + j * 16) * 2048 +
                    (seq0 + i * 16)) = pk.u;
        }
    }
  } else if constexpr (MODE == 1) {
    __hip_bfloat16* C = (__hip_bfloat16*)Cv + (long)z * sCb;
    float* srow = sums + z * 2048;
#pragma unroll
    for (int i = 0; i < 4; ++i)
#pragma unroll
      for (int r = 0; r < 4; ++r) {
        const int m = row0 + i * 16 + r;
        long ro = (long)m * ldc;
        float sp = 0.f;
#pragma unroll
        for (int j = 0; j < 4; ++j) {
          const int n = col0 + j * 16;
          float p = (n <= m) ? __expf(acc[i][j][r] * scale) : 0.0f;
          sp += p;
          C[ro + n] = __float2bfloat16(p);
        }
        sp += __shfl_xor(sp, 1);
        sp += __shfl_xor(sp, 2);
        sp += __shfl_xor(sp, 4);
        sp += __shfl_xor(sp, 8);
        if ((l & 15) == 0) atomicAdd(&srow[m], sp);
      }
  } else {
    float* C = (float*)Cv + (long)z * sCb;
    const float* srow = sums + z * 2048;
#pragma unroll
    for (int i = 0; i < 4; ++i)
#pragma unroll
      for (int r = 0; r < 4; ++r) {
        const int m = row0 + i * 16 + r;
        const float s = 1.0f / srow[m];
        long ro = (long)m * ldc;
#pragma unroll
        for (int j = 0; j < 4; ++j)
          C[ro + col0 + j * 16] = acc[i][j][r] * s;
      }
  }
}

// ---------------- launch ----------------
extern "C" void kernel_launch(void* const* d_in, const int* in_sizes, int n_in,
                              void* d_out, int out_size, void* d_ws, size_t ws_size,
                              hipStream_t stream) {
  const float* x  = (const float*)d_in[0];
  const float* Wq = (const float*)d_in[1];
  const float* Wk = (const float*)d_in[2];
  const float* Wv = (const float*)d_in[3];
  float* out = (float*)d_out;
  char* ws = (char*)d_ws;

  // ws layout (bytes):
  //   qkv bf16 [3][8192][1024]   @ 0          (48 MB; v-slice unused now)
  //   vT  bf16 [4][1024][2048]   @ 50331648   (16 MB)
  //   xb  bf16 [8192][1024]      @ 67108864   (16 MB, dead after proj)
  //   Wb  bf16 [3][1024][1024]   @ 83886080   ( 6 MB, dead after proj)
  //   P   bf16 [4][2048][2048]   @ 67108864   (32 MB, overlaps dead xb/Wb)
  //   sums fp32 [8192]           @ 100663296  (32 KB)
  __hip_bfloat16* qkv = (__hip_bfloat16*)ws;
  __hip_bfloat16* vT  = (__hip_bfloat16*)(ws + 50331648);
  __hip_bfloat16* xb  = (__hip_bfloat16*)(ws + 67108864);
  __hip_bfloat16* Wb  = (__hip_bfloat16*)(ws + 83886080);
  __hip_bfloat16* P   = (__hip_bfloat16*)(ws + 67108864);
  float* sums         = (float*)(ws + 100663296);

  hipMemsetAsync(sums, 0, 8192 * sizeof(float), stream);

  cast_f32_bf16<<<8192, 256, 0, stream>>>(x, xb, 8388608);
  cast_w3<<<3072, 256, 0, stream>>>(Wq, Wk, Wv, Wb);

  // qkv projections; z==2 (V) written transposed into vT by the epilogue
  gemm_nt<0><<<dim3(24, 64, 1), 256, 0, stream>>>(
      xb, 0L, 1024, Wb, 1048576L, 1024, qkv, 8388608L, 1024,
      1024, 1.0f, nullptr, vT);

  // P = exp((q@k^T)/32) causal, bf16, fused row-sums (triangular grid: 136*4)
  gemm_nt<1><<<dim3(544, 1, 1), 256, 0, stream>>>(
      qkv, 2097152L, 1024, qkv + 8388608, 2097152L, 1024,
      P, 4194304L, 2048, 1024, 0.03125f, sums, nullptr);

  // out = (P @ vT^T) / rowsum, causal K-limit, pair-balanced flat grid
  gemm_nt<2><<<dim3(512, 1, 1), 256, 0, stream>>>(
      P, 4194304L, 2048, vT, 2097152L, 2048,
      out, 2097152L, 1024, 2048, 1.0f, sums, nullptr);
}

// Round 8
// 232.328 us; speedup vs baseline: 1.0669x; 1.0133x over previous
//
#include <hip/hip_runtime.h>
#include <hip/hip_bf16.h>

typedef __bf16 v8bf __attribute__((ext_vector_type(8)));
typedef float v4f __attribute__((ext_vector_type(4)));

#define GBL_AS(p) ((const __attribute__((address_space(1))) unsigned int*)(p))
#define LDS_AS(p) ((__attribute__((address_space(3))) unsigned int*)(p))

// s_waitcnt immediates: lgkmcnt=15 (no wait) bits[11:8], expcnt=7 bits[6:4],
// vmcnt low bits[3:0].
#define WAIT_VM4() __builtin_amdgcn_s_waitcnt(0x0F74)  // vmcnt(4)
#define WAIT_VM0() __builtin_amdgcn_s_waitcnt(0x0F70)  // vmcnt(0)

// ---------------- fp32 -> bf16 cast (x) ----------------
__global__ void cast_f32_bf16(const float* __restrict__ src,
                              __hip_bfloat16* __restrict__ dst, int n) {
  int i = (blockIdx.x * 256 + threadIdx.x) * 4;
  if (i >= n) return;
  float4 f = *(const float4*)(src + i);
  union { __hip_bfloat16 h[4]; uint2 u; } pk;
  pk.h[0] = __float2bfloat16(f.x);
  pk.h[1] = __float2bfloat16(f.y);
  pk.h[2] = __float2bfloat16(f.z);
  pk.h[3] = __float2bfloat16(f.w);
  *(uint2*)(dst + i) = pk.u;
}

// ---------------- fp32 -> bf16 cast, 3 weight tensors in one dispatch ----------------
__global__ void cast_w3(const float* __restrict__ a, const float* __restrict__ b,
                        const float* __restrict__ c, __hip_bfloat16* __restrict__ dst) {
  int seg = blockIdx.x >> 10;
  const float* src = seg == 0 ? a : (seg == 1 ? b : c);
  int i = ((blockIdx.x & 1023) * 256 + threadIdx.x) * 4;
  float4 f = *(const float4*)(src + i);
  union { __hip_bfloat16 h[4]; uint2 u; } pk;
  pk.h[0] = __float2bfloat16(f.x);
  pk.h[1] = __float2bfloat16(f.y);
  pk.h[2] = __float2bfloat16(f.z);
  pk.h[3] = __float2bfloat16(f.w);
  *(uint2*)(dst + seg * 1048576 + i) = pk.u;
}

// ---------------- NT GEMM: C[m,n] = f( scale * sum_k A[m,k]*B[n,k] ) ----------------
// 128x128 tile, BK=32, 256 threads (4 waves as 2x2 of 64x64), mfma 16x16x32 bf16.
// Triple LDS buffer, raw s_barrier + vmcnt(4) pipeline; K=1024 paths fully
// unrolled (constant-folded addresses).
// LDS XOR-SWIZZLE (new this round): 16B chunk (row r, col-chunk c) lives at
// chunk index r*4 + (c ^ ((r>>1)&3)). Old layout put rows 64B apart = half the
// 128B bank stripe -> 8-way conflicts on every ds_read_b128 (SQ_LDS_BANK_CONFLICT
// 6.29M/dispatch). Swizzle spreads 16 consecutive rows over all 8 bank-groups
// (2-way = free, m136). DMA dest is hardwired base+lane*16, so the swizzle is
// realized by permuting each lane's GLOBAL source chunk (stays within the same
// 64B segment -> coalescing preserved). Read base folds the XOR in once;
// +16-row offsets stay constant (+1024B) since (r>>1)&3 is invariant mod 16.
// MODE 0: proj. grid (24,64). z<2 -> bf16 out to qkv; z==2 -> transposed to vT.
// MODE 1: scores->P. triangular grid (544). p=(n<=m)?exp(s*scale):0, fused
//         row-sum atomicAdd.
// MODE 2: PV (dynamic K). paired grid (512), mirrored mb. fp32 out / sums[m].
template<int MODE>
__global__ __launch_bounds__(256, 3)
void gemm_nt(const __hip_bfloat16* __restrict__ A, long sAb, int lda,
             const __hip_bfloat16* __restrict__ B, long sBb, int ldb,
             void* __restrict__ Cv, long sCb, int ldc,
             int K, float scale, float* __restrict__ sums,
             __hip_bfloat16* __restrict__ vTp) {
  const int tid = threadIdx.x;
  const int l = tid & 63, w = tid >> 6;
  int z, nb, mb, kend = K;
  if (MODE == 0) {
    z = blockIdx.x >> 3; nb = (blockIdx.x & 7) << 7; mb = blockIdx.y << 7;
  } else if (MODE == 1) {
    const int id = blockIdx.x;
    z = id & 3;
    const int t = id >> 2;                         // 0..135 triangular index
    int m = (int)((__builtin_sqrtf(8.0f * t + 1.0f) - 1.0f) * 0.5f);
    while ((m + 1) * (m + 2) / 2 <= t) ++m;
    while (m * (m + 1) / 2 > t) --m;
    mb = m << 7;
    nb = (t - m * (m + 1) / 2) << 7;
  } else {
    const int id = blockIdx.x;
    const int half = id >> 8, r8 = id & 255;
    const int m = r8 >> 4, low = r8 & 15;
    nb = (low >> 1) << 7;
    z = (half << 1) | (low & 1);
    const int mi = half ? (15 - m) : m;            // mirrored: pair work constant
    mb = mi << 7;
    kend = (mi + 1) << 7;                          // causal K-limit
  }

  A += (long)z * sAb;
  B += (long)z * sBb;

  __shared__ alignas(16) __hip_bfloat16 As[3][128 * 32];
  __shared__ alignas(16) __hip_bfloat16 Bs[3][128 * 32];

  v4f acc[4][4] = {};
  const int wm = (w >> 1) * 64, wn = (w & 1) * 64;

  // staging: lane l fills LDS chunk q = cb + l; that chunk holds global
  // (row = q>>2, col-chunk = (q&3) ^ ((row>>1)&3))   [swizzle inverse]
  const int cb0 = w * 64;
  const int q0 = cb0 + l, r0s = q0 >> 2;
  const int c0s = ((q0 & 3) ^ ((r0s >> 1) & 3)) << 3;
  const int cb1 = 256 + w * 64;
  const int q1 = cb1 + l, r1s = q1 >> 2;
  const int c1s = ((q1 & 3) ^ ((r1s >> 1) & 3)) << 3;

  const __hip_bfloat16* Arow0 = A + (long)(mb + r0s) * lda + c0s;
  const __hip_bfloat16* Arow1 = A + (long)(mb + r1s) * lda + c1s;
  const __hip_bfloat16* Brow0 = B + (long)(nb + r0s) * ldb + c0s;
  const __hip_bfloat16* Brow1 = B + (long)(nb + r1s) * ldb + c1s;

  // swizzled LDS read bases: row = wm/wn + (l&15), col-chunk = l>>4
  const int arow = wm + (l & 15);
  const int ldsA = arow * 32 + ((((l >> 4) ^ ((arow >> 1) & 3))) << 3);
  const int brow = wn + (l & 15);
  const int ldsB = brow * 32 + ((((l >> 4) ^ ((brow >> 1) & 3))) << 3);

  // K0 = element offset (compile-time constant in unrolled path); offset arg 0.
#define STAGE_T(K0, BUF) do {                                                   \
    __builtin_amdgcn_global_load_lds(GBL_AS(Arow0 + (K0)),                      \
        LDS_AS(&As[BUF][cb0 * 8]), 16, 0, 0);                                   \
    __builtin_amdgcn_global_load_lds(GBL_AS(Brow0 + (K0)),                      \
        LDS_AS(&Bs[BUF][cb0 * 8]), 16, 0, 0);                                   \
    __builtin_amdgcn_global_load_lds(GBL_AS(Arow1 + (K0)),                      \
        LDS_AS(&As[BUF][cb1 * 8]), 16, 0, 0);                                   \
    __builtin_amdgcn_global_load_lds(GBL_AS(Brow1 + (K0)),                      \
        LDS_AS(&Bs[BUF][cb1 * 8]), 16, 0, 0);                                   \
  } while (0)

#define COMPUTE(BI) do {                                                        \
    v8bf af[4], bfr[4];                                                         \
    _Pragma("unroll")                                                           \
    for (int i = 0; i < 4; ++i) {                                               \
      af[i]  = *(const v8bf*)(&As[BI][ldsA + i * 512]);                         \
      bfr[i] = *(const v8bf*)(&Bs[BI][ldsB + i * 512]);                         \
    }                                                                           \
    _Pragma("unroll")                                                           \
    for (int i = 0; i < 4; ++i)                                                 \
      _Pragma("unroll")                                                         \
      for (int j = 0; j < 4; ++j)                                               \
        acc[i][j] = __builtin_amdgcn_mfma_f32_16x16x32_bf16(af[i], bfr[j],      \
                                                            acc[i][j], 0, 0, 0);\
  } while (0)

#define KITER(IT) do {                                                          \
    if constexpr ((IT) < 31) WAIT_VM4(); else WAIT_VM0();                       \
    __builtin_amdgcn_s_barrier();                                               \
    if constexpr ((IT) < 30) STAGE_T((IT) * 32 + 64, ((IT) + 2) % 3);           \
    COMPUTE((IT) % 3);                                                          \
  } while (0)

  if constexpr (MODE == 0 || MODE == 1) {
    // K = 1024 = 32 tiles, fully unrolled, constant-folded addresses
    STAGE_T(0, 0);
    STAGE_T(32, 1);
    KITER(0);  KITER(1);  KITER(2);  KITER(3);  KITER(4);  KITER(5);  KITER(6);
    KITER(7);  KITER(8);  KITER(9);  KITER(10); KITER(11); KITER(12); KITER(13);
    KITER(14); KITER(15); KITER(16); KITER(17); KITER(18); KITER(19); KITER(20);
    KITER(21); KITER(22); KITER(23); KITER(24); KITER(25); KITER(26); KITER(27);
    KITER(28); KITER(29); KITER(30); KITER(31);
  } else {
    // dynamic K (PV): rolling 3-buffer pipeline
    auto stage = [&](int k0, int buf) {
      __builtin_amdgcn_global_load_lds(GBL_AS(Arow0 + k0),
          LDS_AS(&As[buf][cb0 * 8]), 16, 0, 0);
      __builtin_amdgcn_global_load_lds(GBL_AS(Brow0 + k0),
          LDS_AS(&Bs[buf][cb0 * 8]), 16, 0, 0);
      __builtin_amdgcn_global_load_lds(GBL_AS(Arow1 + k0),
          LDS_AS(&As[buf][cb1 * 8]), 16, 0, 0);
      __builtin_amdgcn_global_load_lds(GBL_AS(Brow1 + k0),
          LDS_AS(&Bs[buf][cb1 * 8]), 16, 0, 0);
    };
    stage(0, 0);
    if (32 < kend) stage(32, 1);
    int bi = 0;
    for (int k0 = 0; k0 < kend; k0 += 32) {
      if (k0 + 32 < kend) WAIT_VM4(); else WAIT_VM0();
      __builtin_amdgcn_s_barrier();
      if (k0 + 64 < kend) stage(k0 + 64, bi == 0 ? 2 : bi - 1);
      v8bf af[4], bfr[4];
#pragma unroll
      for (int i = 0; i < 4; ++i) {
        af[i]  = *(const v8bf*)(&As[bi][ldsA + i * 512]);
        bfr[i] = *(const v8bf*)(&Bs[bi][ldsB + i * 512]);
      }
#pragma unroll
      for (int i = 0; i < 4; ++i)
#pragma unroll
        for (int j = 0; j < 4; ++j)
          acc[i][j] = __builtin_amdgcn_mfma_f32_16x16x32_bf16(af[i], bfr[j], acc[i][j], 0, 0, 0);
      bi = (bi == 2) ? 0 : bi + 1;
    }
  }
#undef KITER
#undef COMPUTE
#undef STAGE_T

  // epilogue: C/D layout col=lane&15, row=(lane>>4)*4+reg  [m89-verified]
  const int col0 = nb + wn + (l & 15);
  const int row0 = mb + wm + ((l >> 4) << 2);
  if constexpr (MODE == 0) {
    if (z < 2) {
      __hip_bfloat16* C = (__hip_bfloat16*)Cv + (long)z * sCb;
#pragma unroll
      for (int i = 0; i < 4; ++i)
#pragma unroll
        for (int r = 0; r < 4; ++r) {
          long ro = (long)(row0 + i * 16 + r) * ldc;
#pragma unroll
          for (int j = 0; j < 4; ++j)
            C[ro + col0 + j * 16] = __float2bfloat16(acc[i][j][r] * scale);
        }
    } else {
      // V projection: write transposed into vT[b][col][seq], 8B packed stores
      const long b = row0 >> 11;
      const int seq0 = row0 & 2047;
#pragma unroll
      for (int i = 0; i < 4; ++i)
#pragma unroll
        for (int j = 0; j < 4; ++j) {
          union { __hip_bfloat16 h[4]; uint2 u; } pk;
#pragma unroll
          for (int r = 0; r < 4; ++r) pk.h[r] = __float2bfloat16(acc[i][j][r]);
          *(uint2*)(vTp + b * 2097152 + (long)(col0 + j * 16) * 2048 +
                    (seq0 + i * 16)) = pk.u;
        }
    }
  } else if constexpr (MODE == 1) {
    __hip_bfloat16* C = (__hip_bfloat16*)Cv + (long)z * sCb;
    float* srow = sums + z * 2048;
#pragma unroll
    for (int i = 0; i < 4; ++i)
#pragma unroll
      for (int r = 0; r < 4; ++r) {
        const int m = row0 + i * 16 + r;
        long ro = (long)m * ldc;
        float sp = 0.f;
#pragma unroll
        for (int j = 0; j < 4; ++j) {
          const int n = col0 + j * 16;
          float p = (n <= m) ? __expf(acc[i][j][r] * scale) : 0.0f;
          sp += p;
          C[ro + n] = __float2bfloat16(p);
        }
        sp += __shfl_xor(sp, 1);
        sp += __shfl_xor(sp, 2);
        sp += __shfl_xor(sp, 4);
        sp += __shfl_xor(sp, 8);
        if ((l & 15) == 0) atomicAdd(&srow[m], sp);
      }
  } else {
    float* C = (float*)Cv + (long)z * sCb;
    const float* srow = sums + z * 2048;
#pragma unroll
    for (int i = 0; i < 4; ++i)
#pragma unroll
      for (int r = 0; r < 4; ++r) {
        const int m = row0 + i * 16 + r;
        const float s = 1.0f / srow[m];
        long ro = (long)m * ldc;
#pragma unroll
        for (int j = 0; j < 4; ++j)
          C[ro + col0 + j * 16] = acc[i][j][r] * s;
      }
  }
}

// ---------------- launch ----------------
extern "C" void kernel_launch(void* const* d_in, const int* in_sizes, int n_in,
                              void* d_out, int out_size, void* d_ws, size_t ws_size,
                              hipStream_t stream) {
  const float* x  = (const float*)d_in[0];
  const float* Wq = (const float*)d_in[1];
  const float* Wk = (const float*)d_in[2];
  const float* Wv = (const float*)d_in[3];
  float* out = (float*)d_out;
  char* ws = (char*)d_ws;

  // ws layout (bytes):
  //   qkv bf16 [3][8192][1024]   @ 0          (48 MB; v-slice unused now)
  //   vT  bf16 [4][1024][2048]   @ 50331648   (16 MB)
  //   xb  bf16 [8192][1024]      @ 67108864   (16 MB, dead after proj)
  //   Wb  bf16 [3][1024][1024]   @ 83886080   ( 6 MB, dead after proj)
  //   P   bf16 [4][2048][2048]   @ 67108864   (32 MB, overlaps dead xb/Wb)
  //   sums fp32 [8192]           @ 100663296  (32 KB)
  __hip_bfloat16* qkv = (__hip_bfloat16*)ws;
  __hip_bfloat16* vT  = (__hip_bfloat16*)(ws + 50331648);
  __hip_bfloat16* xb  = (__hip_bfloat16*)(ws + 67108864);
  __hip_bfloat16* Wb  = (__hip_bfloat16*)(ws + 83886080);
  __hip_bfloat16* P   = (__hip_bfloat16*)(ws + 67108864);
  float* sums         = (float*)(ws + 100663296);

  hipMemsetAsync(sums, 0, 8192 * sizeof(float), stream);

  cast_f32_bf16<<<8192, 256, 0, stream>>>(x, xb, 8388608);
  cast_w3<<<3072, 256, 0, stream>>>(Wq, Wk, Wv, Wb);

  // qkv projections; z==2 (V) written transposed into vT by the epilogue
  gemm_nt<0><<<dim3(24, 64, 1), 256, 0, stream>>>(
      xb, 0L, 1024, Wb, 1048576L, 1024, qkv, 8388608L, 1024,
      1024, 1.0f, nullptr, vT);

  // P = exp((q@k^T)/32) causal, bf16, fused row-sums (triangular grid: 136*4)
  gemm_nt<1><<<dim3(544, 1, 1), 256, 0, stream>>>(
      qkv, 2097152L, 1024, qkv + 8388608, 2097152L, 1024,
      P, 4194304L, 2048, 1024, 0.03125f, sums, nullptr);

  // out = (P @ vT^T) / rowsum, causal K-limit, pair-balanced flat grid
  gemm_nt<2><<<dim3(512, 1, 1), 256, 0, stream>>>(
      P, 4194304L, 2048, vT, 2097152L, 2048,
      out, 2097152L, 1024, 2048, 1.0f, sums, nullptr);
}